// Round 6
// baseline (291.260 us; speedup 1.0000x reference)
//
#include <hip/hip_runtime.h>
#include <math.h>

#define Bn 128
#define Hh 32
#define Wx 1024

#define N1f 4198400.0f   // 128*32*1025
#define N2f 131200.0f    // 128*1025
#define N3f 33024.0f     // 128*258

// ---- ws float offsets ----
#define OFF_EH     33    // 15
#define OFF_ET     48    // 15
#define OFF_G      64    // 480
#define OFF_G2     544   // 480
#define OFF_A1     1024  // 16
#define OFF_B1     1040  // 16
#define OFF_S1_3   1056  // 32
#define OFF_S2_3   1088  // 32
#define OFF_SEG    1120  // 132
#define OFF_CNT    1252  // 4
#define OFF_DSQ    1256  // 4
#define ZERO_N     1280
#define OFF_PC     2048                   // 32*1024 autocorr partials [d][blk]
#define OFF_PS     34816                  // 1024 sum partials
#define OFF_PD1    35840                  // 32*512 BN2 s1 partials [oc][z*128+b]
#define OFF_PD2    52224                  // 32*512 BN2 s2 partials
#define OFF_DWOUT  68608                  // 128*32*1024 (stride 1024)
#define OFF_E2     (68608 + 4194304)      // 128*32*258 = 1056768
// DWOUT dead after k_pe -> overlay
#define OFF_C3     OFF_DWOUT              // 128*32*258
#define OFF_PTS    (OFF_C3 + 1056768)     // 128*64*33
#define OFF_VO     (OFF_PTS + 270336)     // 128*64*33

__device__ __forceinline__ float eluf(float x) { return x > 0.f ? x : expm1f(x); }

// ---------------- K0: edge sums G, G2, EH, ET ----------------
// grid 64, block 256; block handles 64 rows.
__global__ __launch_bounds__(256) void k_edge(const float* __restrict__ x,
                                              float* __restrict__ ws) {
    __shared__ float hd[64 * 48];
    __shared__ float tl[64 * 48];
    int tid = threadIdx.x;
    int r0 = blockIdx.x * 64;
    for (int i = tid; i < 64 * 32; i += 256) {
        int r = i >> 5, c = i & 31;
        tl[r * 48 + 16 + c] = 0.f;
    }
#pragma unroll
    for (int it = 0; it < 4; it++) {
        int idx = tid + it * 256;
        int r = idx >> 4, q = idx & 15;
        const float4* base = (const float4*)(x + (r0 + r) * Wx);
        if (q < 12) ((float4*)(hd + r * 48))[q] = base[q];
        else        ((float4*)(tl + r * 48))[q - 12] = base[252 + (q - 12)];
    }
    __syncthreads();
    for (int p = tid; p < 990; p += 256) {
        float acc = 0.f;
        if (p < 480) {
            int d = p / 15, j = p - d * 15;
            for (int r = 0; r < 64; r++) acc += hd[r * 48 + j] * hd[r * 48 + j + d];
            atomicAdd(&ws[OFF_G + p], acc);
        } else if (p < 960) {
            int p2 = p - 480;
            int d = p2 / 15, j = p2 - d * 15;
            for (int r = 0; r < 64; r++) acc += tl[r * 48 + 1 + j] * tl[r * 48 + 1 + j + d];
            atomicAdd(&ws[OFF_G2 + p2], acc);
        } else {
            int j = p - 960;
            if (j < 15) { for (int r = 0; r < 64; r++) acc += hd[r * 48 + j]; }
            else        { for (int r = 0; r < 64; r++) acc += tl[r * 48 + 1 + (j - 15)]; }
            atomicAdd(&ws[OFF_EH + j], acc);
        }
    }
}

// ---------------- K1: lag-autocorrelation C[d] + total sum, per-block partials ----
// grid 1024, block 256; block handles 4 rows, double-buffered.
__global__ __launch_bounds__(256, 1) void k_corr(const float* __restrict__ x,
                                                 float* __restrict__ ws) {
    __shared__ float xs[2][1060];
    __shared__ float cacc[32];
    __shared__ float sacc;
    int tid = threadIdx.x;
    if (tid < 32) cacc[tid] = 0.f;
    if (tid == 32) sacc = 0.f;
    for (int i = 1024 + tid; i < 1060; i += 256) { xs[0][i] = 0.f; xs[1][i] = 0.f; }
    float acc[32];
#pragma unroll
    for (int d = 0; d < 32; d++) acc[d] = 0.f;
    float sp = 0.f;
    int r0 = blockIdx.x * 4;
    ((float4*)xs[0])[tid] = ((const float4*)(x + r0 * Wx))[tid];
    __syncthreads();
    for (int rr = 0; rr < 4; rr++) {
        float4 nxt;
        if (rr < 3) nxt = ((const float4*)(x + (r0 + rr + 1) * Wx))[tid];
        const float* bq = xs[rr & 1];
        float v[36];
#pragma unroll
        for (int q = 0; q < 9; q++) {
            float4 t4 = ((const float4*)bq)[tid + q];
            v[4 * q] = t4.x; v[4 * q + 1] = t4.y; v[4 * q + 2] = t4.z; v[4 * q + 3] = t4.w;
        }
#pragma unroll
        for (int i = 0; i < 4; i++) {
            sp += v[i];
#pragma unroll
            for (int d = 0; d < 32; d++) acc[d] += v[i] * v[i + d];
        }
        if (rr < 3) ((float4*)xs[(rr + 1) & 1])[tid] = nxt;
        __syncthreads();
    }
    int lane = tid & 63;
#pragma unroll
    for (int d = 0; d < 32; d++) {
        float vv = acc[d];
#pragma unroll
        for (int off = 32; off > 0; off >>= 1) vv += __shfl_down(vv, off);
        if (lane == 0) atomicAdd(&cacc[d], vv);
    }
    {
        float vv = sp;
#pragma unroll
        for (int off = 32; off > 0; off >>= 1) vv += __shfl_down(vv, off);
        if (lane == 0) atomicAdd(&sacc, vv);
    }
    __syncthreads();
    if (tid < 32) ws[OFF_PC + tid * 1024 + blockIdx.x] = cacc[tid];
    if (tid == 32) ws[OFF_PS + blockIdx.x] = sacc;
}

// ---------------- K1b: reduce partials + assemble BN1 affine ----------------
__global__ __launch_bounds__(512) void k_fold(const float* __restrict__ w1,
                                              const float* __restrict__ bn1w,
                                              const float* __restrict__ bn1b,
                                              float* __restrict__ ws) {
    __shared__ float PH[32][16];
    __shared__ float PT[32][16];
    __shared__ float Ts[32];
    __shared__ float w1s[512];
    __shared__ float sumsq[16];
    __shared__ float meanv[16];
    __shared__ float Cs[32];
    __shared__ float sS[16];
    int tid = threadIdx.x;
    w1s[tid] = w1[tid];
    if (tid < 16) sumsq[tid] = 0.f;
    {   // C prepass: 32 lags x 16 threads, 64 blocks each
        int d = tid >> 4, i = tid & 15;
        const float4* pc = (const float4*)(ws + OFF_PC + d * 1024 + i * 64);
        float s = 0.f;
#pragma unroll
        for (int k = 0; k < 16; k++) { float4 t4 = pc[k]; s += t4.x + t4.y + t4.z + t4.w; }
        s += __shfl_down(s, 8); s += __shfl_down(s, 4);
        s += __shfl_down(s, 2); s += __shfl_down(s, 1);
        if (i == 0) Cs[d] = s;
    }
    __syncthreads();
    if (tid < 32) {
        int d = tid;
        float s = 0.f;
        for (int j = 0; j < 15; j++) { s += ws[OFF_G + d * 15 + j]; PH[d][j] = s; }
        float s2 = 0.f;
        for (int j = 14; j >= 0; j--) { s2 += ws[OFF_G2 + d * 15 + j]; PT[d][j] = s2; }
    } else if (tid < 48) {  // S prepass
        int i = tid - 32;
        const float4* ps = (const float4*)(ws + OFF_PS + i * 64);
        float s = 0.f;
#pragma unroll
        for (int k = 0; k < 16; k++) { float4 t4 = ps[k]; s += t4.x + t4.y + t4.z + t4.w; }
        sS[i] = s;
    }
    __syncthreads();
    if (tid >= 64 && tid < 96) {
        int k = tid - 64;
        float S = 0.f;
        for (int j = 0; j < 16; j++) S += sS[j];
        float t = S;
        for (int j = 0; j <= k - 17; j++) t -= ws[OFF_EH + j];
        if (k <= 14) for (int j = k; j < 15; j++) t -= ws[OFF_ET + j];
        Ts[k] = t;
    }
    __syncthreads();
    int c = tid >> 5, d = tid & 31;
    float Cd = Cs[d];
    float part = 0.f;
    for (int k = 0; k + d < 32; k++) {
        float head = (k >= 17) ? PH[d][k - 17] : 0.f;
        float tail = (k <= 14) ? PT[d][k] : 0.f;
        float R = Cd - head - tail;
        part += w1s[c * 32 + k] * w1s[c * 32 + k + d] * R;
    }
    if (d > 0) part *= 2.f;
    atomicAdd(&sumsq[c], part);
    if (d == 0) {
        float mp = 0.f;
        for (int k = 0; k < 32; k++) mp += w1s[c * 32 + k] * Ts[k];
        meanv[c] = mp / N1f;
    }
    __syncthreads();
    if (tid < 16) {
        float mean = meanv[tid];
        float var = fmaxf(sumsq[tid] / N1f - mean * mean, 0.f);
        float a = bn1w[tid] / sqrtf(var + 1e-3f);
        ws[OFF_A1 + tid] = a;
        ws[OFF_B1 + tid] = bn1b[tid] - mean * a;
    }
}

// ---------------- K2: conv1+bn1+dw via Y-fold; grid (128,4,4) ----------------
// block: batch b, oc [8y,8y+8), w-tile [256z,256z+256)
__global__ __launch_bounds__(256, 1) void k_dw(const float* __restrict__ x,
                                               const float* __restrict__ w1,
                                               const float* __restrict__ dww,
                                               float* __restrict__ ws) {
    __shared__ float dws[256];
    __shared__ float w1s[128];
    __shared__ float Dv[8];
    __shared__ float a1s[4], b1s[4];
    __shared__ float Ys[8 * 296];
    __shared__ float st[16];
    int tid = threadIdx.x;
    int b = blockIdx.x;
    int ocb = blockIdx.y * 8;
    int z = blockIdx.z;
    int wt0 = z * 256;
    int g0 = ocb >> 1;
    dws[tid] = dww[ocb * 32 + tid];
    if (tid < 128) w1s[tid] = w1[g0 * 32 + tid];
    if (tid < 16) st[tid] = 0.f;
    if (tid < 4) { a1s[tid] = ws[OFF_A1 + g0 + tid]; b1s[tid] = ws[OFF_B1 + g0 + tid]; }
    __syncthreads();
    if (tid < 8) {
        float d = 0.f;
        for (int h = 0; h < 32; h++) d += dws[tid * 32 + h];
        Dv[tid] = d;
    }
    // Phase A: Y(j,p) for p in [wt0, wt0+288)
    for (int p = wt0 + tid; p < wt0 + 288; p += 256) {
        float acc[8];
#pragma unroll
        for (int j = 0; j < 8; j++) acc[j] = 0.f;
        bool inr = (p >= 16 && p < 16 + Wx);
        const float* xb = x + b * (Hh * Wx) + (p - 16);
        for (int h = 0; h < Hh; h++) {
            float xv = inr ? xb[h << 10] : 0.f;
#pragma unroll
            for (int j = 0; j < 8; j++) acc[j] += xv * dws[j * 32 + h];
        }
#pragma unroll
        for (int j = 0; j < 8; j++) Ys[j * 296 + (p - wt0)] = acc[j];
    }
    __syncthreads();
    // Phase B: one w per thread, lane-stride-1 b32 reads (conflict-free)
    int w = wt0 + tid;
    int lane = tid & 63;
    for (int jp = 0; jp < 4; jp++) {
        float wr[32];
#pragma unroll
        for (int k = 0; k < 32; k++) wr[k] = w1s[jp * 32 + k];
#pragma unroll
        for (int jj = 0; jj < 2; jj++) {
            int j = jp * 2 + jj;
            float s = 0.f;
#pragma unroll 8
            for (int k = 0; k < 32; k++) s += wr[k] * Ys[j * 296 + tid + k];
            float val = a1s[jp] * s + b1s[jp] * Dv[j];
            ws[OFF_DWOUT + (b * 32 + ocb + j) * 1024 + w] = val;
            float ls1 = val, ls2 = val * val;
            if (z == 3 && tid == 0) {  // w=1024 tail: stats only
                float s2 = 0.f;
#pragma unroll
                for (int k = 0; k < 32; k++) s2 += wr[k] * Ys[j * 296 + 256 + k];
                float v2 = a1s[jp] * s2 + b1s[jp] * Dv[j];
                ls1 += v2; ls2 += v2 * v2;
            }
#pragma unroll
            for (int off = 32; off > 0; off >>= 1) {
                ls1 += __shfl_down(ls1, off);
                ls2 += __shfl_down(ls2, off);
            }
            if (lane == 0) { atomicAdd(&st[j], ls1); atomicAdd(&st[8 + j], ls2); }
        }
    }
    __syncthreads();
    if (tid < 8)       ws[OFF_PD1 + (ocb + tid) * 512 + z * 128 + b] = st[tid];
    else if (tid < 16) ws[OFF_PD2 + (ocb + tid - 8) * 512 + z * 128 + b] = st[tid];
}

// ---------------- K3: BN2+ELU+pool4 + ec1 + b2c1 per (b,c); stats from partials ----
__global__ __launch_bounds__(64) void k_pe(const float* __restrict__ ec1w,
                                           const float* __restrict__ bc1w,
                                           const float* __restrict__ bn2w,
                                           const float* __restrict__ bn2b,
                                           float* __restrict__ ws) {
    __shared__ float ins[272];
    __shared__ float e1p[288];
    int b = blockIdx.x, c = blockIdx.y;
    int t = threadIdx.x;
    if (t < 8) { ins[t] = 0.f; ins[264 + t] = 0.f; e1p[t] = 0.f; }
    if (t < 23) e1p[265 + t] = 0.f;
    // reduce BN2 stats from 512 partials
    const float4* p1 = (const float4*)(ws + OFF_PD1 + c * 512);
    const float4* p2 = (const float4*)(ws + OFF_PD2 + c * 512);
    float4 a0 = p1[t * 2], a1 = p1[t * 2 + 1], c0 = p2[t * 2], c1 = p2[t * 2 + 1];
    float s1 = a0.x + a0.y + a0.z + a0.w + a1.x + a1.y + a1.z + a1.w;
    float s2 = c0.x + c0.y + c0.z + c0.w + c1.x + c1.y + c1.z + c1.w;
#pragma unroll
    for (int off = 32; off > 0; off >>= 1) {
        s1 += __shfl_xor(s1, off);
        s2 += __shfl_xor(s2, off);
    }
    float mean = s1 / N2f;
    float var = fmaxf(s2 / N2f - mean * mean, 0.f);
    float a = bn2w[c] / sqrtf(var + 1e-3f);
    float bb = bn2b[c] - mean * a;
    const float4* dr = (const float4*)(ws + OFF_DWOUT + (b * 32 + c) * 1024);
#pragma unroll
    for (int q = 0; q < 4; q++) {
        float4 v4 = dr[q * 64 + t];
        ins[8 + q * 64 + t] = 0.25f * (eluf(a * v4.x + bb) + eluf(a * v4.y + bb) +
                                       eluf(a * v4.z + bb) + eluf(a * v4.w + bb));
    }
    __syncthreads();
    float ek[16], bk[16];
#pragma unroll
    for (int k = 0; k < 16; k++) { ek[k] = ec1w[c * 16 + k]; bk[k] = bc1w[c * 16 + k]; }
    for (int w = t; w < 257; w += 64) {
        float s = 0.f;
#pragma unroll
        for (int k = 0; k < 16; k++) s += ins[w + k] * ek[k];
        e1p[8 + w] = s;
    }
    __syncthreads();
    float* e2r = ws + OFF_E2 + (b * 32 + c) * 258;
    for (int w = t; w < 258; w += 64) {
        float s = 0.f;
#pragma unroll
        for (int k = 0; k < 16; k++) s += e1p[w + k] * bk[k];
        e2r[w] = s;
    }
}

// ---------------- K4: b2c2 (1x1 dense) + BN3 stats ----------------
__global__ __launch_bounds__(256) void k_sep2(const float* __restrict__ bc2w,
                                              float* __restrict__ ws) {
    __shared__ float es[32 * 129];
    __shared__ float bs[1056];
    int b = blockIdx.x;
    int wb = blockIdx.y * 129;
    int t = threadIdx.x;
    for (int i = t; i < 1024; i += 256) { int o = i >> 5, cc = i & 31; bs[o * 33 + cc] = bc2w[i]; }
    const float* e2b = ws + OFF_E2 + b * 8256;
    for (int i = t; i < 4128; i += 256) {
        int cc = i / 129, wl = i - cc * 129;
        es[i] = e2b[cc * 258 + wb + wl];
    }
    __syncthreads();
    int o = t >> 3, w0 = t & 7;
    float wr[32];
#pragma unroll
    for (int cc = 0; cc < 32; cc++) wr[cc] = bs[o * 33 + cc];
    float s1 = 0.f, s2 = 0.f;
    float* c3r = ws + OFF_C3 + (b * 32 + o) * 258 + wb;
    for (int wl = w0; wl < 129; wl += 8) {
        float s = 0.f;
#pragma unroll
        for (int cc = 0; cc < 32; cc++) s += es[cc * 129 + wl] * wr[cc];
        c3r[wl] = s;
        s1 += s; s2 += s * s;
    }
    s1 += __shfl_down(s1, 4, 8); s1 += __shfl_down(s1, 2, 8); s1 += __shfl_down(s1, 1, 8);
    s2 += __shfl_down(s2, 4, 8); s2 += __shfl_down(s2, 2, 8); s2 += __shfl_down(s2, 1, 8);
    if (w0 == 0) {
        atomicAdd(&ws[OFF_S1_3 + o], s1);
        atomicAdd(&ws[OFF_S2_3 + o], s2);
    }
}

// ---------------- K5: BN3+ELU+pool4 + normalize + lift + lc1 -> pts ----------------
__global__ __launch_bounds__(256, 1) void k_head(const float* __restrict__ bn3w,
                                                 const float* __restrict__ bn3b,
                                                 const float* __restrict__ lc1w,
                                                 const int* __restrict__ domains,
                                                 float* __restrict__ ws) {
    __shared__ float q[2048];
    __shared__ float lc1s[1089];
    __shared__ float psum[33];
    __shared__ float ssyp[4][64];
    __shared__ float a3s[32], b3s[32];
    int tid = threadIdx.x;
    int b = blockIdx.x;
    if (tid < 32) {
        float mean = ws[OFF_S1_3 + tid] / N3f;
        float var = fmaxf(ws[OFF_S2_3 + tid] / N3f - mean * mean, 0.f);
        float a = bn3w[tid] / sqrtf(var + 1e-3f);
        a3s[tid] = a;
        b3s[tid] = bn3b[tid] - mean * a;
    }
    for (int i = tid; i < 1089; i += 256) lc1s[i] = lc1w[i];
    __syncthreads();
    const float* c3 = ws + OFF_C3 + b * 8256;
    for (int idx = tid; idx < 2048; idx += 256) {
        int c = idx >> 6, wp = idx & 63;
        float a = a3s[c], bb = b3s[c];
        float acc = 0.f;
#pragma unroll
        for (int j = 0; j < 4; j++) {
            float e = a * c3[c * 258 + wp * 4 + j] + bb;
            acc += eluf(e);
        }
        q[idx] = 0.25f * acc;
    }
    __syncthreads();
    int w = tid & 63, sub = tid >> 6;
    float qv[32];
    float ssq = 0.f;
#pragma unroll
    for (int c = 0; c < 32; c++) { qv[c] = q[c * 64 + w]; ssq += qv[c] * qv[c]; }
    float inv = 1.f / fmaxf(sqrtf(ssq), 1e-12f);
    float ss2 = 0.f;
#pragma unroll
    for (int c = 0; c < 32; c++) { qv[c] *= inv; ss2 += qv[c] * qv[c]; }
    float t = sqrtf(1.f + ss2);
    int o0 = 1 + sub * 8;
    float p[8];
    float ssy_part = 0.f;
#pragma unroll
    for (int i = 0; i < 8; i++) {
        int o = o0 + i;
        float s = lc1s[o * 33] * t;
#pragma unroll
        for (int c = 0; c < 32; c++) s += lc1s[o * 33 + 1 + c] * qv[c];
        p[i] = s;
        ssy_part += s * s;
    }
    ssyp[sub][w] = ssy_part;
    float* pr = ws + OFF_PTS + (b * 64 + w) * 33;
#pragma unroll
    for (int i = 0; i < 8; i++) pr[o0 + i] = p[i];
    __syncthreads();
    float yt = 0.f;
    if (sub == 0) {
        float ssy = ssyp[0][w] + ssyp[1][w] + ssyp[2][w] + ssyp[3][w];
        yt = sqrtf(1.f + ssy);
        pr[0] = yt;
    }
#pragma unroll
    for (int i = 0; i < 8; i++) {
        float vv = p[i];
#pragma unroll
        for (int off = 32; off > 0; off >>= 1) vv += __shfl_down(vv, off);
        if (w == 0) psum[o0 + i] = vv;
    }
    {
        float vv = yt;
#pragma unroll
        for (int off = 32; off > 0; off >>= 1) vv += __shfl_down(vv, off);
        if (w == 0 && sub == 0) psum[0] = vv;
    }
    __syncthreads();
    int dom = domains[b];
    if (tid < 33) atomicAdd(&ws[OFF_SEG + dom * 33 + tid], psum[tid]);
    if (tid == 64) atomicAdd(&ws[OFF_CNT + dom], 64.f);
}

// ---------------- K6: mu (inline) + log-map + transport + dist^2 ----------------
__global__ __launch_bounds__(64, 1) void k_tangent(const int* __restrict__ domains,
                                                   float* __restrict__ ws) {
    int b = blockIdx.x;
    int w = threadIdx.x;
    int dom = domains[b];
    float cnt = fmaxf(ws[OFF_CNT + dom], 1.f);
    float m[33];
    float s0 = ws[OFF_SEG + dom * 33] / cnt;
    m[0] = s0;
    float msum = 0.f;
#pragma unroll
    for (int c = 1; c < 33; c++) {
        m[c] = ws[OFF_SEG + dom * 33 + c] / cnt;
        msum += m[c] * m[c];
    }
    float mkm = -s0 * s0 + msum;
    float dn = 1.f / sqrtf(fmaxf(fabsf(mkm), 1e-8f));
#pragma unroll
    for (int c = 0; c < 33; c++) m[c] *= dn;
    const float* pr = ws + OFF_PTS + (b * 64 + w) * 33;
    float p[33];
#pragma unroll
    for (int c = 0; c < 33; c++) p[c] = pr[c];
    float ip = -m[0] * p[0];
#pragma unroll
    for (int c = 1; c < 33; c++) ip += m[c] * p[c];
    float z = fmaxf(-ip, 1.f + 1e-7f);
    float dist = acoshf(z);
    float u[33];
#pragma unroll
    for (int c = 0; c < 33; c++) u[c] = p[c] + ip * m[c];
    float mk = -u[0] * u[0];
#pragma unroll
    for (int c = 1; c < 33; c++) mk += u[c] * u[c];
    float un = sqrtf(fmaxf(mk, 1e-8f));
    float r = dist / un;
    float v0 = r * u[0];
    float coef = -v0 / (1.f + m[0]);
    float* vo = ws + OFF_VO + (b * 64 + w) * 33;
    vo[0] = v0 + coef * (m[0] + 1.f);
#pragma unroll
    for (int c = 1; c < 33; c++) vo[c] = r * u[c] + coef * m[c];
    float dsq = dist * dist;
#pragma unroll
    for (int off = 32; off > 0; off >>= 1) dsq += __shfl_down(dsq, off);
    if (w == 0) atomicAdd(&ws[OFF_DSQ + dom], dsq);
}

// ---------------- K7: scale, transport to beta, expmap, L-ELU, L-pool, MLR ----------
__global__ __launch_bounds__(64, 1) void k_final(const int* __restrict__ domains,
                                                 const float* __restrict__ beta,
                                                 const float* __restrict__ gamma,
                                                 const float* __restrict__ mlr_a,
                                                 const float* __restrict__ mlr_z,
                                                 float* __restrict__ ws,
                                                 float* __restrict__ out) {
    __shared__ float he[64 * 33];
    __shared__ float hp[16 * 33];
    int b = blockIdx.x;
    int w = threadIdx.x;
    int dom = domains[b];
    float cnt = fmaxf(ws[OFF_CNT + dom], 1.f);
    float var = ws[OFF_DSQ + dom] / cnt;
    float sc = gamma[0] / sqrtf(var + 1e-5f);
    float bt[33];
#pragma unroll
    for (int c = 0; c < 33; c++) bt[c] = beta[c];
    const float* vo = ws + OFF_VO + (b * 64 + w) * 33;
    float v[33];
#pragma unroll
    for (int c = 0; c < 33; c++) v[c] = vo[c] * sc;
    float mb = -bt[0] * v[0];
#pragma unroll
    for (int c = 1; c < 33; c++) mb += bt[c] * v[c];
    float coef = mb / (1.f + bt[0]);
    v[0] += coef * (1.f + bt[0]);
#pragma unroll
    for (int c = 1; c < 33; c++) v[c] += coef * bt[c];
    float mk = -v[0] * v[0];
#pragma unroll
    for (int c = 1; c < 33; c++) mk += v[c] * v[c];
    float vn = sqrtf(fmaxf(mk, 1e-8f));
    float ch = coshf(vn), sh = sinhf(vn) / vn;
    float ss = 0.f;
#pragma unroll
    for (int c = 1; c < 33; c++) {
        float y = ch * bt[c] + sh * v[c];
        float s = eluf(y);
        he[w * 33 + c] = s;
        ss += s * s;
    }
    he[w * 33] = sqrtf(1.f + ss);
    __syncthreads();
    if (w < 16) {
        float tmp[33];
        float mk2;
        {
            float a0 = 0.25f * (he[(4 * w) * 33] + he[(4 * w + 1) * 33] +
                                he[(4 * w + 2) * 33] + he[(4 * w + 3) * 33]);
            tmp[0] = a0;
            mk2 = -a0 * a0;
        }
#pragma unroll
        for (int c = 1; c < 33; c++) {
            float a = 0.25f * (he[(4 * w) * 33 + c] + he[(4 * w + 1) * 33 + c] +
                               he[(4 * w + 2) * 33 + c] + he[(4 * w + 3) * 33 + c]);
            tmp[c] = a;
            mk2 += a * a;
        }
        float dd = sqrtf(fmaxf(fabsf(mk2), 1e-8f));
#pragma unroll
        for (int c = 0; c < 33; c++) hp[w * 33 + c] = tmp[c] / dd;
    }
    __syncthreads();
    float ssq = 0.f, sdz = 0.f, zz = 0.f;
    for (int j = w; j < 512; j += 64) {
        float val = hp[(j >> 5) * 33 + 1 + (j & 31)];
        float zv = mlr_z[j];
        ssq += val * val;
        sdz += val * zv;
        zz += zv * zv;
        out[128 + b * 513 + 1 + j] = val;
    }
#pragma unroll
    for (int off = 32; off > 0; off >>= 1) {
        ssq += __shfl_down(ssq, off);
        sdz += __shfl_down(sdz, off);
        zz += __shfl_down(zz, off);
    }
    if (w == 0) {
        float nz = sqrtf(zz);
        float a = mlr_a[0];
        float cha = coshf(a);
        float wt = sinhf(a) * nz;
        float cn = cha * nz;
        float bet = sqrtf(fmaxf(cn * cn - wt * wt, 1e-8f));
        float ft = sqrtf(1.f + ssq);
        float alpha = -wt * ft + cha * sdz;
        out[128 + b * 513] = ft;
        out[b] = bet * asinhf(alpha / bet);
    }
}

extern "C" void kernel_launch(void* const* d_in, const int* in_sizes, int n_in,
                              void* d_out, int out_size, void* d_ws, size_t ws_size,
                              hipStream_t stream) {
    const float* x       = (const float*)d_in[0];
    const int*   domains = (const int*)d_in[1];
    const float* conv1_w = (const float*)d_in[2];
    const float* bn1_w   = (const float*)d_in[3];
    const float* bn1_b   = (const float*)d_in[4];
    const float* dw_w    = (const float*)d_in[5];
    const float* bn2_w   = (const float*)d_in[6];
    const float* bn2_b   = (const float*)d_in[7];
    const float* ec1_w   = (const float*)d_in[8];
    const float* b2c1_w  = (const float*)d_in[9];
    const float* b2c2_w  = (const float*)d_in[10];
    const float* bn3_w   = (const float*)d_in[11];
    const float* bn3_b   = (const float*)d_in[12];
    const float* lc1_w   = (const float*)d_in[13];
    const float* bn_beta = (const float*)d_in[14];
    const float* bn_gamma= (const float*)d_in[15];
    const float* mlr_a   = (const float*)d_in[16];
    const float* mlr_z   = (const float*)d_in[17];
    float* out = (float*)d_out;
    float* ws  = (float*)d_ws;

    hipMemsetAsync(ws, 0, ZERO_N * sizeof(float), stream);
    k_edge<<<64, 256, 0, stream>>>(x, ws);
    k_corr<<<1024, 256, 0, stream>>>(x, ws);
    k_fold<<<1, 512, 0, stream>>>(conv1_w, bn1_w, bn1_b, ws);
    k_dw<<<dim3(128, 4, 4), 256, 0, stream>>>(x, conv1_w, dw_w, ws);
    k_pe<<<dim3(128, 32), 64, 0, stream>>>(ec1_w, b2c1_w, bn2_w, bn2_b, ws);
    k_sep2<<<dim3(128, 2), 256, 0, stream>>>(b2c2_w, ws);
    k_head<<<Bn, 256, 0, stream>>>(bn3_w, bn3_b, lc1_w, domains, ws);
    k_tangent<<<Bn, 64, 0, stream>>>(domains, ws);
    k_final<<<Bn, 64, 0, stream>>>(domains, bn_beta, bn_gamma, mlr_a, mlr_z, ws, out);
}

// Round 7
// 275.579 us; speedup vs baseline: 1.0569x; 1.0569x over previous
//
#include <hip/hip_runtime.h>
#include <math.h>

#define Bn 128
#define Hh 32
#define Wx 1024

#define N1f 4198400.0f   // 128*32*1025
#define N2f 131200.0f    // 128*1025
#define N3f 33024.0f     // 128*258

// ---- ws float offsets ----
#define OFF_EH     33    // 15
#define OFF_ET     48    // 15
#define OFF_G      64    // 480
#define OFF_G2     544   // 480
#define OFF_A1     1024  // 16
#define OFF_B1     1040  // 16
#define OFF_S1_3   1056  // 32
#define OFF_S2_3   1088  // 32
#define OFF_SEG    1120  // 132
#define OFF_CNT    1252  // 4
#define OFF_DSQ    1256  // 4
#define ZERO_N     1280
#define OFF_PC     2048                   // 32*1024 autocorr partials [d][blk]
#define OFF_PS     34816                  // 1024 sum partials
#define OFF_PD1    35840                  // 32*256 BN2 s1 partials [oc][z*128+b]
#define OFF_PD2    44032                  // 32*256 BN2 s2 partials
#define OFF_DWOUT  52224                  // 128*32*1024 (stride 1024)
#define OFF_E2     (52224 + 4194304)      // 128*32*258 = 1056768
// DWOUT dead after k_pe -> overlay
#define OFF_C3     OFF_DWOUT              // 128*32*258
#define OFF_PTS    (OFF_C3 + 1056768)     // 128*64*33
#define OFF_VO     (OFF_PTS + 270336)     // 128*64*33

__device__ __forceinline__ float eluf(float x) { return x > 0.f ? x : expm1f(x); }

// ---------------- K0: edge sums G, G2, EH, ET ----------------
__global__ __launch_bounds__(256) void k_edge(const float* __restrict__ x,
                                              float* __restrict__ ws) {
    __shared__ float hd[64 * 48];
    __shared__ float tl[64 * 48];
    int tid = threadIdx.x;
    int r0 = blockIdx.x * 64;
    for (int i = tid; i < 64 * 32; i += 256) {
        int r = i >> 5, c = i & 31;
        tl[r * 48 + 16 + c] = 0.f;
    }
#pragma unroll
    for (int it = 0; it < 4; it++) {
        int idx = tid + it * 256;
        int r = idx >> 4, q = idx & 15;
        const float4* base = (const float4*)(x + (r0 + r) * Wx);
        if (q < 12) ((float4*)(hd + r * 48))[q] = base[q];
        else        ((float4*)(tl + r * 48))[q - 12] = base[252 + (q - 12)];
    }
    __syncthreads();
    for (int p = tid; p < 990; p += 256) {
        float acc = 0.f;
        if (p < 480) {
            int d = p / 15, j = p - d * 15;
            for (int r = 0; r < 64; r++) acc += hd[r * 48 + j] * hd[r * 48 + j + d];
            atomicAdd(&ws[OFF_G + p], acc);
        } else if (p < 960) {
            int p2 = p - 480;
            int d = p2 / 15, j = p2 - d * 15;
            for (int r = 0; r < 64; r++) acc += tl[r * 48 + 1 + j] * tl[r * 48 + 1 + j + d];
            atomicAdd(&ws[OFF_G2 + p2], acc);
        } else {
            int j = p - 960;
            if (j < 15) { for (int r = 0; r < 64; r++) acc += hd[r * 48 + j]; }
            else        { for (int r = 0; r < 64; r++) acc += tl[r * 48 + 1 + (j - 15)]; }
            atomicAdd(&ws[OFF_EH + j], acc);
        }
    }
}

// ---------------- K1: lag-autocorrelation C[d] + total sum, per-block partials ----
__global__ __launch_bounds__(256, 1) void k_corr(const float* __restrict__ x,
                                                 float* __restrict__ ws) {
    __shared__ float xs[2][1060];
    __shared__ float cacc[32];
    __shared__ float sacc;
    int tid = threadIdx.x;
    if (tid < 32) cacc[tid] = 0.f;
    if (tid == 32) sacc = 0.f;
    for (int i = 1024 + tid; i < 1060; i += 256) { xs[0][i] = 0.f; xs[1][i] = 0.f; }
    float acc[32];
#pragma unroll
    for (int d = 0; d < 32; d++) acc[d] = 0.f;
    float sp = 0.f;
    int r0 = blockIdx.x * 4;
    ((float4*)xs[0])[tid] = ((const float4*)(x + r0 * Wx))[tid];
    __syncthreads();
    for (int rr = 0; rr < 4; rr++) {
        float4 nxt;
        if (rr < 3) nxt = ((const float4*)(x + (r0 + rr + 1) * Wx))[tid];
        const float* bq = xs[rr & 1];
        float v[36];
#pragma unroll
        for (int q = 0; q < 9; q++) {
            float4 t4 = ((const float4*)bq)[tid + q];
            v[4 * q] = t4.x; v[4 * q + 1] = t4.y; v[4 * q + 2] = t4.z; v[4 * q + 3] = t4.w;
        }
#pragma unroll
        for (int i = 0; i < 4; i++) {
            sp += v[i];
#pragma unroll
            for (int d = 0; d < 32; d++) acc[d] += v[i] * v[i + d];
        }
        if (rr < 3) ((float4*)xs[(rr + 1) & 1])[tid] = nxt;
        __syncthreads();
    }
    int lane = tid & 63;
#pragma unroll
    for (int d = 0; d < 32; d++) {
        float vv = acc[d];
#pragma unroll
        for (int off = 32; off > 0; off >>= 1) vv += __shfl_down(vv, off);
        if (lane == 0) atomicAdd(&cacc[d], vv);
    }
    {
        float vv = sp;
#pragma unroll
        for (int off = 32; off > 0; off >>= 1) vv += __shfl_down(vv, off);
        if (lane == 0) atomicAdd(&sacc, vv);
    }
    __syncthreads();
    if (tid < 32) ws[OFF_PC + tid * 1024 + blockIdx.x] = cacc[tid];
    if (tid == 32) ws[OFF_PS + blockIdx.x] = sacc;
}

// ---------------- K1b: reduce partials + assemble BN1 affine ----------------
__global__ __launch_bounds__(512) void k_fold(const float* __restrict__ w1,
                                              const float* __restrict__ bn1w,
                                              const float* __restrict__ bn1b,
                                              float* __restrict__ ws) {
    __shared__ float PH[32][16];
    __shared__ float PT[32][16];
    __shared__ float Ts[32];
    __shared__ float w1s[512];
    __shared__ float sumsq[16];
    __shared__ float meanv[16];
    __shared__ float Cs[32];
    __shared__ float sS[16];
    int tid = threadIdx.x;
    w1s[tid] = w1[tid];
    if (tid < 16) sumsq[tid] = 0.f;
    {   // C prepass
        int d = tid >> 4, i = tid & 15;
        const float4* pc = (const float4*)(ws + OFF_PC + d * 1024 + i * 64);
        float s = 0.f;
#pragma unroll
        for (int k = 0; k < 16; k++) { float4 t4 = pc[k]; s += t4.x + t4.y + t4.z + t4.w; }
        s += __shfl_down(s, 8); s += __shfl_down(s, 4);
        s += __shfl_down(s, 2); s += __shfl_down(s, 1);
        if (i == 0) Cs[d] = s;
    }
    __syncthreads();
    if (tid < 32) {
        int d = tid;
        float s = 0.f;
        for (int j = 0; j < 15; j++) { s += ws[OFF_G + d * 15 + j]; PH[d][j] = s; }
        float s2 = 0.f;
        for (int j = 14; j >= 0; j--) { s2 += ws[OFF_G2 + d * 15 + j]; PT[d][j] = s2; }
    } else if (tid < 48) {
        int i = tid - 32;
        const float4* ps = (const float4*)(ws + OFF_PS + i * 64);
        float s = 0.f;
#pragma unroll
        for (int k = 0; k < 16; k++) { float4 t4 = ps[k]; s += t4.x + t4.y + t4.z + t4.w; }
        sS[i] = s;
    }
    __syncthreads();
    if (tid >= 64 && tid < 96) {
        int k = tid - 64;
        float S = 0.f;
        for (int j = 0; j < 16; j++) S += sS[j];
        float t = S;
        for (int j = 0; j <= k - 17; j++) t -= ws[OFF_EH + j];
        if (k <= 14) for (int j = k; j < 15; j++) t -= ws[OFF_ET + j];
        Ts[k] = t;
    }
    __syncthreads();
    int c = tid >> 5, d = tid & 31;
    float Cd = Cs[d];
    float part = 0.f;
    for (int k = 0; k + d < 32; k++) {
        float head = (k >= 17) ? PH[d][k - 17] : 0.f;
        float tail = (k <= 14) ? PT[d][k] : 0.f;
        float R = Cd - head - tail;
        part += w1s[c * 32 + k] * w1s[c * 32 + k + d] * R;
    }
    if (d > 0) part *= 2.f;
    atomicAdd(&sumsq[c], part);
    if (d == 0) {
        float mp = 0.f;
        for (int k = 0; k < 32; k++) mp += w1s[c * 32 + k] * Ts[k];
        meanv[c] = mp / N1f;
    }
    __syncthreads();
    if (tid < 16) {
        float mean = meanv[tid];
        float var = fmaxf(sumsq[tid] / N1f - mean * mean, 0.f);
        float a = bn1w[tid] / sqrtf(var + 1e-3f);
        ws[OFF_A1 + tid] = a;
        ws[OFF_B1 + tid] = bn1b[tid] - mean * a;
    }
}

// ---------------- K2: conv1+bn1+dw via Y-fold; grid (128,4,2) ----------------
// block: batch b, oc [8y,8y+8), w-tile [512z, 512z+512)
__global__ __launch_bounds__(256, 2) void k_dw(const float* __restrict__ x,
                                               const float* __restrict__ w1,
                                               const float* __restrict__ dww,
                                               float* __restrict__ ws) {
    __shared__ float dws[256];
    __shared__ float w1s[128];
    __shared__ float Dv[8];
    __shared__ float a1s[4], b1s[4];
    __shared__ float Ys[8 * 552];
    __shared__ float st[16];
    int tid = threadIdx.x;
    int b = blockIdx.x;
    int ocb = blockIdx.y * 8;
    int z = blockIdx.z;
    int wt0 = z * 512;
    int g0 = ocb >> 1;
    dws[tid] = dww[ocb * 32 + tid];
    if (tid < 128) w1s[tid] = w1[g0 * 32 + tid];
    if (tid < 16) st[tid] = 0.f;
    if (tid < 4) { a1s[tid] = ws[OFF_A1 + g0 + tid]; b1s[tid] = ws[OFF_B1 + g0 + tid]; }
    __syncthreads();
    if (tid < 8) {
        float d = 0.f;
        for (int h = 0; h < 32; h++) d += dws[tid * 32 + h];
        Dv[tid] = d;
    }
    // Phase A: Y(j,pp) for pp in [0,544); 32 independent loads per pass (ILP)
    for (int pp = tid; pp < 544; pp += 256) {
        int p = wt0 + pp;
        bool inr = (p >= 16 && p < 16 + Wx);
        const float* xb = x + b * (Hh * Wx) + (p - 16);
        float xv[32];
#pragma unroll
        for (int h = 0; h < 32; h++) xv[h] = inr ? xb[h << 10] : 0.f;
        float acc[8];
#pragma unroll
        for (int j = 0; j < 8; j++) acc[j] = 0.f;
#pragma unroll
        for (int h = 0; h < 32; h++) {
#pragma unroll
            for (int j = 0; j < 8; j++) acc[j] += xv[h] * dws[j * 32 + h];
        }
#pragma unroll
        for (int j = 0; j < 8; j++) Ys[j * 552 + pp] = acc[j];
    }
    __syncthreads();
    // Phase B: one w per thread per pass, lane-stride-1 b32 reads (conflict-free)
    int lane = tid & 63;
    for (int jp = 0; jp < 4; jp++) {
        float wr[32];
#pragma unroll
        for (int k = 0; k < 32; k++) wr[k] = w1s[jp * 32 + k];
#pragma unroll
        for (int jj = 0; jj < 2; jj++) {
            int j = jp * 2 + jj;
            float ls1 = 0.f, ls2 = 0.f;
#pragma unroll
            for (int pass = 0; pass < 2; pass++) {
                int wl = pass * 256 + tid;
                float s = 0.f;
#pragma unroll 8
                for (int k = 0; k < 32; k++) s += wr[k] * Ys[j * 552 + wl + k];
                float val = a1s[jp] * s + b1s[jp] * Dv[j];
                ws[OFF_DWOUT + (b * 32 + ocb + j) * 1024 + wt0 + wl] = val;
                ls1 += val; ls2 += val * val;
            }
            if (z == 1 && tid == 0) {  // w=1024 tail: stats only
                float s2 = 0.f;
#pragma unroll
                for (int k = 0; k < 32; k++) s2 += wr[k] * Ys[j * 552 + 512 + k];
                float v2 = a1s[jp] * s2 + b1s[jp] * Dv[j];
                ls1 += v2; ls2 += v2 * v2;
            }
#pragma unroll
            for (int off = 32; off > 0; off >>= 1) {
                ls1 += __shfl_down(ls1, off);
                ls2 += __shfl_down(ls2, off);
            }
            if (lane == 0) { atomicAdd(&st[j], ls1); atomicAdd(&st[8 + j], ls2); }
        }
    }
    __syncthreads();
    if (tid < 8)       ws[OFF_PD1 + (ocb + tid) * 256 + z * 128 + b] = st[tid];
    else if (tid < 16) ws[OFF_PD2 + (ocb + tid - 8) * 256 + z * 128 + b] = st[tid];
}

// ---------------- K3: BN2+ELU+pool4 + ec1 + b2c1 per (b,c); stats from partials ----
__global__ __launch_bounds__(64) void k_pe(const float* __restrict__ ec1w,
                                           const float* __restrict__ bc1w,
                                           const float* __restrict__ bn2w,
                                           const float* __restrict__ bn2b,
                                           float* __restrict__ ws) {
    __shared__ float ins[272];
    __shared__ float e1p[288];
    int b = blockIdx.x, c = blockIdx.y;
    int t = threadIdx.x;
    if (t < 8) { ins[t] = 0.f; ins[264 + t] = 0.f; e1p[t] = 0.f; }
    if (t < 23) e1p[265 + t] = 0.f;
    // reduce BN2 stats from 256 partials
    const float4* p1 = (const float4*)(ws + OFF_PD1 + c * 256);
    const float4* p2 = (const float4*)(ws + OFF_PD2 + c * 256);
    float4 a0 = p1[t];
    float4 c0 = p2[t];
    float s1 = a0.x + a0.y + a0.z + a0.w;
    float s2 = c0.x + c0.y + c0.z + c0.w;
#pragma unroll
    for (int off = 32; off > 0; off >>= 1) {
        s1 += __shfl_xor(s1, off);
        s2 += __shfl_xor(s2, off);
    }
    float mean = s1 / N2f;
    float var = fmaxf(s2 / N2f - mean * mean, 0.f);
    float a = bn2w[c] / sqrtf(var + 1e-3f);
    float bb = bn2b[c] - mean * a;
    const float4* dr = (const float4*)(ws + OFF_DWOUT + (b * 32 + c) * 1024);
#pragma unroll
    for (int q = 0; q < 4; q++) {
        float4 v4 = dr[q * 64 + t];
        ins[8 + q * 64 + t] = 0.25f * (eluf(a * v4.x + bb) + eluf(a * v4.y + bb) +
                                       eluf(a * v4.z + bb) + eluf(a * v4.w + bb));
    }
    __syncthreads();
    float ek[16], bk[16];
#pragma unroll
    for (int k = 0; k < 16; k++) { ek[k] = ec1w[c * 16 + k]; bk[k] = bc1w[c * 16 + k]; }
    for (int w = t; w < 257; w += 64) {
        float s = 0.f;
#pragma unroll
        for (int k = 0; k < 16; k++) s += ins[w + k] * ek[k];
        e1p[8 + w] = s;
    }
    __syncthreads();
    float* e2r = ws + OFF_E2 + (b * 32 + c) * 258;
    for (int w = t; w < 258; w += 64) {
        float s = 0.f;
#pragma unroll
        for (int k = 0; k < 16; k++) s += e1p[w + k] * bk[k];
        e2r[w] = s;
    }
}

// ---------------- K4: b2c2 (1x1 dense) + BN3 stats ----------------
__global__ __launch_bounds__(256) void k_sep2(const float* __restrict__ bc2w,
                                              float* __restrict__ ws) {
    __shared__ float es[32 * 129];
    __shared__ float bs[1056];
    int b = blockIdx.x;
    int wb = blockIdx.y * 129;
    int t = threadIdx.x;
    for (int i = t; i < 1024; i += 256) { int o = i >> 5, cc = i & 31; bs[o * 33 + cc] = bc2w[i]; }
    const float* e2b = ws + OFF_E2 + b * 8256;
    for (int i = t; i < 4128; i += 256) {
        int cc = i / 129, wl = i - cc * 129;
        es[i] = e2b[cc * 258 + wb + wl];
    }
    __syncthreads();
    int o = t >> 3, w0 = t & 7;
    float wr[32];
#pragma unroll
    for (int cc = 0; cc < 32; cc++) wr[cc] = bs[o * 33 + cc];
    float s1 = 0.f, s2 = 0.f;
    float* c3r = ws + OFF_C3 + (b * 32 + o) * 258 + wb;
    for (int wl = w0; wl < 129; wl += 8) {
        float s = 0.f;
#pragma unroll
        for (int cc = 0; cc < 32; cc++) s += es[cc * 129 + wl] * wr[cc];
        c3r[wl] = s;
        s1 += s; s2 += s * s;
    }
    s1 += __shfl_down(s1, 4, 8); s1 += __shfl_down(s1, 2, 8); s1 += __shfl_down(s1, 1, 8);
    s2 += __shfl_down(s2, 4, 8); s2 += __shfl_down(s2, 2, 8); s2 += __shfl_down(s2, 1, 8);
    if (w0 == 0) {
        atomicAdd(&ws[OFF_S1_3 + o], s1);
        atomicAdd(&ws[OFF_S2_3 + o], s2);
    }
}

// ---------------- K5: BN3+ELU+pool4 + normalize + lift + lc1 -> pts ----------------
__global__ __launch_bounds__(256, 1) void k_head(const float* __restrict__ bn3w,
                                                 const float* __restrict__ bn3b,
                                                 const float* __restrict__ lc1w,
                                                 const int* __restrict__ domains,
                                                 float* __restrict__ ws) {
    __shared__ float q[2048];
    __shared__ float lc1s[1089];
    __shared__ float psum[33];
    __shared__ float ssyp[4][64];
    __shared__ float a3s[32], b3s[32];
    int tid = threadIdx.x;
    int b = blockIdx.x;
    if (tid < 32) {
        float mean = ws[OFF_S1_3 + tid] / N3f;
        float var = fmaxf(ws[OFF_S2_3 + tid] / N3f - mean * mean, 0.f);
        float a = bn3w[tid] / sqrtf(var + 1e-3f);
        a3s[tid] = a;
        b3s[tid] = bn3b[tid] - mean * a;
    }
    for (int i = tid; i < 1089; i += 256) lc1s[i] = lc1w[i];
    __syncthreads();
    const float* c3 = ws + OFF_C3 + b * 8256;
    for (int idx = tid; idx < 2048; idx += 256) {
        int c = idx >> 6, wp = idx & 63;
        float a = a3s[c], bb = b3s[c];
        float acc = 0.f;
#pragma unroll
        for (int j = 0; j < 4; j++) {
            float e = a * c3[c * 258 + wp * 4 + j] + bb;
            acc += eluf(e);
        }
        q[idx] = 0.25f * acc;
    }
    __syncthreads();
    int w = tid & 63, sub = tid >> 6;
    float qv[32];
    float ssq = 0.f;
#pragma unroll
    for (int c = 0; c < 32; c++) { qv[c] = q[c * 64 + w]; ssq += qv[c] * qv[c]; }
    float inv = 1.f / fmaxf(sqrtf(ssq), 1e-12f);
    float ss2 = 0.f;
#pragma unroll
    for (int c = 0; c < 32; c++) { qv[c] *= inv; ss2 += qv[c] * qv[c]; }
    float t = sqrtf(1.f + ss2);
    int o0 = 1 + sub * 8;
    float p[8];
    float ssy_part = 0.f;
#pragma unroll
    for (int i = 0; i < 8; i++) {
        int o = o0 + i;
        float s = lc1s[o * 33] * t;
#pragma unroll
        for (int c = 0; c < 32; c++) s += lc1s[o * 33 + 1 + c] * qv[c];
        p[i] = s;
        ssy_part += s * s;
    }
    ssyp[sub][w] = ssy_part;
    float* pr = ws + OFF_PTS + (b * 64 + w) * 33;
#pragma unroll
    for (int i = 0; i < 8; i++) pr[o0 + i] = p[i];
    __syncthreads();
    float yt = 0.f;
    if (sub == 0) {
        float ssy = ssyp[0][w] + ssyp[1][w] + ssyp[2][w] + ssyp[3][w];
        yt = sqrtf(1.f + ssy);
        pr[0] = yt;
    }
#pragma unroll
    for (int i = 0; i < 8; i++) {
        float vv = p[i];
#pragma unroll
        for (int off = 32; off > 0; off >>= 1) vv += __shfl_down(vv, off);
        if (w == 0) psum[o0 + i] = vv;
    }
    {
        float vv = yt;
#pragma unroll
        for (int off = 32; off > 0; off >>= 1) vv += __shfl_down(vv, off);
        if (w == 0 && sub == 0) psum[0] = vv;
    }
    __syncthreads();
    int dom = domains[b];
    if (tid < 33) atomicAdd(&ws[OFF_SEG + dom * 33 + tid], psum[tid]);
    if (tid == 64) atomicAdd(&ws[OFF_CNT + dom], 64.f);
}

// ---------------- K6: mu (inline) + log-map + transport + dist^2 ----------------
__global__ __launch_bounds__(64, 1) void k_tangent(const int* __restrict__ domains,
                                                   float* __restrict__ ws) {
    int b = blockIdx.x;
    int w = threadIdx.x;
    int dom = domains[b];
    float cnt = fmaxf(ws[OFF_CNT + dom], 1.f);
    float m[33];
    float s0 = ws[OFF_SEG + dom * 33] / cnt;
    m[0] = s0;
    float msum = 0.f;
#pragma unroll
    for (int c = 1; c < 33; c++) {
        m[c] = ws[OFF_SEG + dom * 33 + c] / cnt;
        msum += m[c] * m[c];
    }
    float mkm = -s0 * s0 + msum;
    float dn = 1.f / sqrtf(fmaxf(fabsf(mkm), 1e-8f));
#pragma unroll
    for (int c = 0; c < 33; c++) m[c] *= dn;
    const float* pr = ws + OFF_PTS + (b * 64 + w) * 33;
    float p[33];
#pragma unroll
    for (int c = 0; c < 33; c++) p[c] = pr[c];
    float ip = -m[0] * p[0];
#pragma unroll
    for (int c = 1; c < 33; c++) ip += m[c] * p[c];
    float z = fmaxf(-ip, 1.f + 1e-7f);
    float dist = acoshf(z);
    float u[33];
#pragma unroll
    for (int c = 0; c < 33; c++) u[c] = p[c] + ip * m[c];
    float mk = -u[0] * u[0];
#pragma unroll
    for (int c = 1; c < 33; c++) mk += u[c] * u[c];
    float un = sqrtf(fmaxf(mk, 1e-8f));
    float r = dist / un;
    float v0 = r * u[0];
    float coef = -v0 / (1.f + m[0]);
    float* vo = ws + OFF_VO + (b * 64 + w) * 33;
    vo[0] = v0 + coef * (m[0] + 1.f);
#pragma unroll
    for (int c = 1; c < 33; c++) vo[c] = r * u[c] + coef * m[c];
    float dsq = dist * dist;
#pragma unroll
    for (int off = 32; off > 0; off >>= 1) dsq += __shfl_down(dsq, off);
    if (w == 0) atomicAdd(&ws[OFF_DSQ + dom], dsq);
}

// ---------------- K7: scale, transport to beta, expmap, L-ELU, L-pool, MLR ----------
__global__ __launch_bounds__(64, 1) void k_final(const int* __restrict__ domains,
                                                 const float* __restrict__ beta,
                                                 const float* __restrict__ gamma,
                                                 const float* __restrict__ mlr_a,
                                                 const float* __restrict__ mlr_z,
                                                 float* __restrict__ ws,
                                                 float* __restrict__ out) {
    __shared__ float he[64 * 33];
    __shared__ float hp[16 * 33];
    int b = blockIdx.x;
    int w = threadIdx.x;
    int dom = domains[b];
    float cnt = fmaxf(ws[OFF_CNT + dom], 1.f);
    float var = ws[OFF_DSQ + dom] / cnt;
    float sc = gamma[0] / sqrtf(var + 1e-5f);
    float bt[33];
#pragma unroll
    for (int c = 0; c < 33; c++) bt[c] = beta[c];
    const float* vo = ws + OFF_VO + (b * 64 + w) * 33;
    float v[33];
#pragma unroll
    for (int c = 0; c < 33; c++) v[c] = vo[c] * sc;
    float mb = -bt[0] * v[0];
#pragma unroll
    for (int c = 1; c < 33; c++) mb += bt[c] * v[c];
    float coef = mb / (1.f + bt[0]);
    v[0] += coef * (1.f + bt[0]);
#pragma unroll
    for (int c = 1; c < 33; c++) v[c] += coef * bt[c];
    float mk = -v[0] * v[0];
#pragma unroll
    for (int c = 1; c < 33; c++) mk += v[c] * v[c];
    float vn = sqrtf(fmaxf(mk, 1e-8f));
    float ch = coshf(vn), sh = sinhf(vn) / vn;
    float ss = 0.f;
#pragma unroll
    for (int c = 1; c < 33; c++) {
        float y = ch * bt[c] + sh * v[c];
        float s = eluf(y);
        he[w * 33 + c] = s;
        ss += s * s;
    }
    he[w * 33] = sqrtf(1.f + ss);
    __syncthreads();
    if (w < 16) {
        float tmp[33];
        float mk2;
        {
            float a0 = 0.25f * (he[(4 * w) * 33] + he[(4 * w + 1) * 33] +
                                he[(4 * w + 2) * 33] + he[(4 * w + 3) * 33]);
            tmp[0] = a0;
            mk2 = -a0 * a0;
        }
#pragma unroll
        for (int c = 1; c < 33; c++) {
            float a = 0.25f * (he[(4 * w) * 33 + c] + he[(4 * w + 1) * 33 + c] +
                               he[(4 * w + 2) * 33 + c] + he[(4 * w + 3) * 33 + c]);
            tmp[c] = a;
            mk2 += a * a;
        }
        float dd = sqrtf(fmaxf(fabsf(mk2), 1e-8f));
#pragma unroll
        for (int c = 0; c < 33; c++) hp[w * 33 + c] = tmp[c] / dd;
    }
    __syncthreads();
    float ssq = 0.f, sdz = 0.f, zz = 0.f;
    for (int j = w; j < 512; j += 64) {
        float val = hp[(j >> 5) * 33 + 1 + (j & 31)];
        float zv = mlr_z[j];
        ssq += val * val;
        sdz += val * zv;
        zz += zv * zv;
        out[128 + b * 513 + 1 + j] = val;
    }
#pragma unroll
    for (int off = 32; off > 0; off >>= 1) {
        ssq += __shfl_down(ssq, off);
        sdz += __shfl_down(sdz, off);
        zz += __shfl_down(zz, off);
    }
    if (w == 0) {
        float nz = sqrtf(zz);
        float a = mlr_a[0];
        float cha = coshf(a);
        float wt = sinhf(a) * nz;
        float cn = cha * nz;
        float bet = sqrtf(fmaxf(cn * cn - wt * wt, 1e-8f));
        float ft = sqrtf(1.f + ssq);
        float alpha = -wt * ft + cha * sdz;
        out[128 + b * 513] = ft;
        out[b] = bet * asinhf(alpha / bet);
    }
}

extern "C" void kernel_launch(void* const* d_in, const int* in_sizes, int n_in,
                              void* d_out, int out_size, void* d_ws, size_t ws_size,
                              hipStream_t stream) {
    const float* x       = (const float*)d_in[0];
    const int*   domains = (const int*)d_in[1];
    const float* conv1_w = (const float*)d_in[2];
    const float* bn1_w   = (const float*)d_in[3];
    const float* bn1_b   = (const float*)d_in[4];
    const float* dw_w    = (const float*)d_in[5];
    const float* bn2_w   = (const float*)d_in[6];
    const float* bn2_b   = (const float*)d_in[7];
    const float* ec1_w   = (const float*)d_in[8];
    const float* b2c1_w  = (const float*)d_in[9];
    const float* b2c2_w  = (const float*)d_in[10];
    const float* bn3_w   = (const float*)d_in[11];
    const float* bn3_b   = (const float*)d_in[12];
    const float* lc1_w   = (const float*)d_in[13];
    const float* bn_beta = (const float*)d_in[14];
    const float* bn_gamma= (const float*)d_in[15];
    const float* mlr_a   = (const float*)d_in[16];
    const float* mlr_z   = (const float*)d_in[17];
    float* out = (float*)d_out;
    float* ws  = (float*)d_ws;

    hipMemsetAsync(ws, 0, ZERO_N * sizeof(float), stream);
    k_edge<<<64, 256, 0, stream>>>(x, ws);
    k_corr<<<1024, 256, 0, stream>>>(x, ws);
    k_fold<<<1, 512, 0, stream>>>(conv1_w, bn1_w, bn1_b, ws);
    k_dw<<<dim3(128, 4, 2), 256, 0, stream>>>(x, conv1_w, dw_w, ws);
    k_pe<<<dim3(128, 32), 64, 0, stream>>>(ec1_w, b2c1_w, bn2_w, bn2_b, ws);
    k_sep2<<<dim3(128, 2), 256, 0, stream>>>(b2c2_w, ws);
    k_head<<<Bn, 256, 0, stream>>>(bn3_w, bn3_b, lc1_w, domains, ws);
    k_tangent<<<Bn, 64, 0, stream>>>(domains, ws);
    k_final<<<Bn, 64, 0, stream>>>(domains, bn_beta, bn_gamma, mlr_a, mlr_z, ws, out);
}

// Round 8
// 237.069 us; speedup vs baseline: 1.2286x; 1.1624x over previous
//
#include <hip/hip_runtime.h>
#include <math.h>

#define Bn 128
#define Hh 32
#define Wx 1024

#define N1f 4198400.0f   // 128*32*1025
#define N2f 131200.0f    // 128*1025
#define N3f 33024.0f     // 128*258

// ---- ws float offsets ----
#define OFF_EH     33    // 15
#define OFF_ET     48    // 15
#define OFF_G      64    // 480
#define OFF_G2     544   // 480
#define OFF_A1     1024  // 16
#define OFF_B1     1040  // 16
#define OFF_S1_3   1056  // 32
#define OFF_S2_3   1088  // 32
#define OFF_SEG    1120  // 132
#define OFF_CNT    1252  // 4
#define OFF_DSQ    1256  // 4
#define ZERO_N     1280
#define OFF_PC     2048                   // 32*1024 autocorr partials [d][blk]
#define OFF_PS     34816                  // 1024 sum partials
#define OFF_PD1    35840                  // 32*512 BN2 s1 partials [oc][z*128+b]
#define OFF_PD2    52224                  // 32*512 BN2 s2 partials
#define OFF_DWOUT  68608                  // 128*32*1024 (stride 1024)
#define OFF_E2     (68608 + 4194304)      // 128*32*258 = 1056768
// DWOUT dead after k_pe -> overlay
#define OFF_C3     OFF_DWOUT              // 128*32*258
#define OFF_PTS    (OFF_C3 + 1056768)     // 128*64*33
#define OFF_VO     (OFF_PTS + 270336)     // 128*64*33

__device__ __forceinline__ float eluf(float x) { return x > 0.f ? x : expm1f(x); }

// ---------------- K0: edge sums G, G2, EH, ET ----------------
__global__ __launch_bounds__(256) void k_edge(const float* __restrict__ x,
                                              float* __restrict__ ws) {
    __shared__ float hd[64 * 48];
    __shared__ float tl[64 * 48];
    int tid = threadIdx.x;
    int r0 = blockIdx.x * 64;
    for (int i = tid; i < 64 * 32; i += 256) {
        int r = i >> 5, c = i & 31;
        tl[r * 48 + 16 + c] = 0.f;
    }
#pragma unroll
    for (int it = 0; it < 4; it++) {
        int idx = tid + it * 256;
        int r = idx >> 4, q = idx & 15;
        const float4* base = (const float4*)(x + (r0 + r) * Wx);
        if (q < 12) ((float4*)(hd + r * 48))[q] = base[q];
        else        ((float4*)(tl + r * 48))[q - 12] = base[252 + (q - 12)];
    }
    __syncthreads();
    for (int p = tid; p < 990; p += 256) {
        float acc = 0.f;
        if (p < 480) {
            int d = p / 15, j = p - d * 15;
            for (int r = 0; r < 64; r++) acc += hd[r * 48 + j] * hd[r * 48 + j + d];
            atomicAdd(&ws[OFF_G + p], acc);
        } else if (p < 960) {
            int p2 = p - 480;
            int d = p2 / 15, j = p2 - d * 15;
            for (int r = 0; r < 64; r++) acc += tl[r * 48 + 1 + j] * tl[r * 48 + 1 + j + d];
            atomicAdd(&ws[OFF_G2 + p2], acc);
        } else {
            int j = p - 960;
            if (j < 15) { for (int r = 0; r < 64; r++) acc += hd[r * 48 + j]; }
            else        { for (int r = 0; r < 64; r++) acc += tl[r * 48 + 1 + (j - 15)]; }
            atomicAdd(&ws[OFF_EH + j], acc);
        }
    }
}

// ---------------- K1: lag-autocorrelation C[d] + total sum, per-block partials ----
__global__ __launch_bounds__(256, 1) void k_corr(const float* __restrict__ x,
                                                 float* __restrict__ ws) {
    __shared__ float xs[2][1060];
    __shared__ float cacc[32];
    __shared__ float sacc;
    int tid = threadIdx.x;
    if (tid < 32) cacc[tid] = 0.f;
    if (tid == 32) sacc = 0.f;
    for (int i = 1024 + tid; i < 1060; i += 256) { xs[0][i] = 0.f; xs[1][i] = 0.f; }
    float acc[32];
#pragma unroll
    for (int d = 0; d < 32; d++) acc[d] = 0.f;
    float sp = 0.f;
    int r0 = blockIdx.x * 4;
    ((float4*)xs[0])[tid] = ((const float4*)(x + r0 * Wx))[tid];
    __syncthreads();
    for (int rr = 0; rr < 4; rr++) {
        float4 nxt;
        if (rr < 3) nxt = ((const float4*)(x + (r0 + rr + 1) * Wx))[tid];
        const float* bq = xs[rr & 1];
        float v[36];
#pragma unroll
        for (int q = 0; q < 9; q++) {
            float4 t4 = ((const float4*)bq)[tid + q];
            v[4 * q] = t4.x; v[4 * q + 1] = t4.y; v[4 * q + 2] = t4.z; v[4 * q + 3] = t4.w;
        }
#pragma unroll
        for (int i = 0; i < 4; i++) {
            sp += v[i];
#pragma unroll
            for (int d = 0; d < 32; d++) acc[d] += v[i] * v[i + d];
        }
        if (rr < 3) ((float4*)xs[(rr + 1) & 1])[tid] = nxt;
        __syncthreads();
    }
    int lane = tid & 63;
#pragma unroll
    for (int d = 0; d < 32; d++) {
        float vv = acc[d];
#pragma unroll
        for (int off = 32; off > 0; off >>= 1) vv += __shfl_down(vv, off);
        if (lane == 0) atomicAdd(&cacc[d], vv);
    }
    {
        float vv = sp;
#pragma unroll
        for (int off = 32; off > 0; off >>= 1) vv += __shfl_down(vv, off);
        if (lane == 0) atomicAdd(&sacc, vv);
    }
    __syncthreads();
    if (tid < 32) ws[OFF_PC + tid * 1024 + blockIdx.x] = cacc[tid];
    if (tid == 32) ws[OFF_PS + blockIdx.x] = sacc;
}

// ---------------- K1b: reduce partials + assemble BN1 affine ----------------
__global__ __launch_bounds__(512) void k_fold(const float* __restrict__ w1,
                                              const float* __restrict__ bn1w,
                                              const float* __restrict__ bn1b,
                                              float* __restrict__ ws) {
    __shared__ float PH[32][16];
    __shared__ float PT[32][16];
    __shared__ float Ts[32];
    __shared__ float w1s[512];
    __shared__ float sumsq[16];
    __shared__ float meanv[16];
    __shared__ float Cs[32];
    __shared__ float sS[16];
    int tid = threadIdx.x;
    w1s[tid] = w1[tid];
    if (tid < 16) sumsq[tid] = 0.f;
    {   // C prepass
        int d = tid >> 4, i = tid & 15;
        const float4* pc = (const float4*)(ws + OFF_PC + d * 1024 + i * 64);
        float s = 0.f;
#pragma unroll
        for (int k = 0; k < 16; k++) { float4 t4 = pc[k]; s += t4.x + t4.y + t4.z + t4.w; }
        s += __shfl_down(s, 8); s += __shfl_down(s, 4);
        s += __shfl_down(s, 2); s += __shfl_down(s, 1);
        if (i == 0) Cs[d] = s;
    }
    __syncthreads();
    if (tid < 32) {
        int d = tid;
        float s = 0.f;
        for (int j = 0; j < 15; j++) { s += ws[OFF_G + d * 15 + j]; PH[d][j] = s; }
        float s2 = 0.f;
        for (int j = 14; j >= 0; j--) { s2 += ws[OFF_G2 + d * 15 + j]; PT[d][j] = s2; }
    } else if (tid < 48) {
        int i = tid - 32;
        const float4* ps = (const float4*)(ws + OFF_PS + i * 64);
        float s = 0.f;
#pragma unroll
        for (int k = 0; k < 16; k++) { float4 t4 = ps[k]; s += t4.x + t4.y + t4.z + t4.w; }
        sS[i] = s;
    }
    __syncthreads();
    if (tid >= 64 && tid < 96) {
        int k = tid - 64;
        float S = 0.f;
        for (int j = 0; j < 16; j++) S += sS[j];
        float t = S;
        for (int j = 0; j <= k - 17; j++) t -= ws[OFF_EH + j];
        if (k <= 14) for (int j = k; j < 15; j++) t -= ws[OFF_ET + j];
        Ts[k] = t;
    }
    __syncthreads();
    int c = tid >> 5, d = tid & 31;
    float Cd = Cs[d];
    float part = 0.f;
    for (int k = 0; k + d < 32; k++) {
        float head = (k >= 17) ? PH[d][k - 17] : 0.f;
        float tail = (k <= 14) ? PT[d][k] : 0.f;
        float R = Cd - head - tail;
        part += w1s[c * 32 + k] * w1s[c * 32 + k + d] * R;
    }
    if (d > 0) part *= 2.f;
    atomicAdd(&sumsq[c], part);
    if (d == 0) {
        float mp = 0.f;
        for (int k = 0; k < 32; k++) mp += w1s[c * 32 + k] * Ts[k];
        meanv[c] = mp / N1f;
    }
    __syncthreads();
    if (tid < 16) {
        float mean = meanv[tid];
        float var = fmaxf(sumsq[tid] / N1f - mean * mean, 0.f);
        float a = bn1w[tid] / sqrtf(var + 1e-3f);
        ws[OFF_A1 + tid] = a;
        ws[OFF_B1 + tid] = bn1b[tid] - mean * a;
    }
}

// ---------------- K2: conv1+bn1+dw via Y-fold; grid (128,4); all 32 oc/block ----
// LDS-staged x tile: x read once per block (coalesced). 2 blocks/CU.
__global__ __launch_bounds__(256, 2) void k_dw(const float* __restrict__ x,
                                               const float* __restrict__ w1,
                                               const float* __restrict__ dww,
                                               float* __restrict__ ws) {
    __shared__ float xs[32 * 288];
    __shared__ float Ys[32 * 288];
    __shared__ float dws[1024];
    __shared__ float w1s[512];
    __shared__ float a1s[16], b1s[16], Dv[32];
    int tid = threadIdx.x;
    int b = blockIdx.x;
    int z = blockIdx.y;
    int wt0 = z * 256;
    // stage weights + BN1 affine
    for (int i = tid; i < 1024; i += 256) dws[i] = dww[i];
    w1s[tid] = w1[tid];
    w1s[256 + tid] = w1[256 + tid];
    if (tid < 16) { a1s[tid] = ws[OFF_A1 + tid]; b1s[tid] = ws[OFF_B1 + tid]; }
    // stage x tile [h][cc], cc in [0,288) -> global col wt0-16+cc (coalesced rows)
    const float* xb = x + b * (Hh * Wx);
    for (int i = tid; i < 32 * 288; i += 256) {
        int h = i / 288, cc = i - h * 288;
        int gc = wt0 - 16 + cc;
        xs[i] = (gc >= 0 && gc < Wx) ? xb[h * Wx + gc] : 0.f;
    }
    __syncthreads();
    if (tid < 32) {
        float d = 0.f;
        for (int h = 0; h < 32; h++) d += dws[tid * 32 + h];
        Dv[tid] = d;
    }
    // Phase A: Y(oc,p) = sum_h xs[h][p]*dw[oc][h]; weights via uniform b128
#pragma unroll
    for (int pass = 0; pass < 2; pass++) {
        int p = pass * 256 + tid;
        if (p < 288) {
            float xv[32];
#pragma unroll
            for (int h = 0; h < 32; h++) xv[h] = xs[h * 288 + p];
#pragma unroll
            for (int ocb = 0; ocb < 4; ocb++) {
                const float4* d4 = (const float4*)(dws + ocb * 256);
                float acc[8];
#pragma unroll
                for (int j = 0; j < 8; j++) acc[j] = 0.f;
#pragma unroll
                for (int j = 0; j < 8; j++) {
#pragma unroll
                    for (int hq = 0; hq < 8; hq++) {
                        float4 dv = d4[j * 8 + hq];
                        acc[j] += xv[4 * hq] * dv.x + xv[4 * hq + 1] * dv.y +
                                  xv[4 * hq + 2] * dv.z + xv[4 * hq + 3] * dv.w;
                    }
                }
#pragma unroll
                for (int j = 0; j < 8; j++) Ys[(ocb * 8 + j) * 288 + p] = acc[j];
            }
        }
    }
    __syncthreads();
    // Phase B: wave = oc-octet, thread = w-quad; 9x b128 window reads
    int wq = tid & 63;
    int wave = tid >> 6;
    int oc0 = wave * 8;
    float ls1[8], ls2[8];
#pragma unroll
    for (int j = 0; j < 8; j++) { ls1[j] = 0.f; ls2[j] = 0.f; }
#pragma unroll
    for (int gp = 0; gp < 4; gp++) {
        int g = wave * 4 + gp;
        float wr[32];
        const float4* wg = (const float4*)(w1s + g * 32);
#pragma unroll
        for (int q = 0; q < 8; q++) {
            float4 t4 = wg[q];
            wr[4 * q] = t4.x; wr[4 * q + 1] = t4.y; wr[4 * q + 2] = t4.z; wr[4 * q + 3] = t4.w;
        }
        float ag = a1s[g], bg = b1s[g];
#pragma unroll
        for (int jj = 0; jj < 2; jj++) {
            int j = gp * 2 + jj;
            int oc = oc0 + j;
            float y[36];
            const float4* yq = (const float4*)(Ys + oc * 288 + 4 * wq);
#pragma unroll
            for (int q = 0; q < 9; q++) {
                float4 t4 = yq[q];
                y[4 * q] = t4.x; y[4 * q + 1] = t4.y; y[4 * q + 2] = t4.z; y[4 * q + 3] = t4.w;
            }
            float bb = bg * Dv[oc];
            float ov[4];
#pragma unroll
            for (int m = 0; m < 4; m++) {
                float s = 0.f;
#pragma unroll
                for (int k = 0; k < 32; k++) s += wr[k] * y[m + k];
                float val = ag * s + bb;
                ov[m] = val;
                ls1[j] += val; ls2[j] += val * val;
            }
            *((float4*)(ws + OFF_DWOUT + (b * 32 + oc) * 1024 + wt0 + 4 * wq)) =
                make_float4(ov[0], ov[1], ov[2], ov[3]);
            if (z == 3 && wq == 63) {  // w=1024 tail: stats only
                float s = 0.f;
#pragma unroll
                for (int k = 0; k < 32; k++) s += wr[k] * Ys[oc * 288 + 256 + k];
                float val = ag * s + bb;
                ls1[j] += val; ls2[j] += val * val;
            }
        }
    }
#pragma unroll
    for (int j = 0; j < 8; j++) {
#pragma unroll
        for (int off = 32; off > 0; off >>= 1) {
            ls1[j] += __shfl_down(ls1[j], off);
            ls2[j] += __shfl_down(ls2[j], off);
        }
    }
    if (wq == 0) {
#pragma unroll
        for (int j = 0; j < 8; j++) {
            ws[OFF_PD1 + (oc0 + j) * 512 + z * 128 + b] = ls1[j];
            ws[OFF_PD2 + (oc0 + j) * 512 + z * 128 + b] = ls2[j];
        }
    }
}

// ---------------- K3: BN2+ELU+pool4 + ec1 + b2c1 per (b,c); stats from partials ----
__global__ __launch_bounds__(64) void k_pe(const float* __restrict__ ec1w,
                                           const float* __restrict__ bc1w,
                                           const float* __restrict__ bn2w,
                                           const float* __restrict__ bn2b,
                                           float* __restrict__ ws) {
    __shared__ float ins[272];
    __shared__ float e1p[288];
    int b = blockIdx.x, c = blockIdx.y;
    int t = threadIdx.x;
    if (t < 8) { ins[t] = 0.f; ins[264 + t] = 0.f; e1p[t] = 0.f; }
    if (t < 23) e1p[265 + t] = 0.f;
    // reduce BN2 stats from 512 partials
    const float4* p1 = (const float4*)(ws + OFF_PD1 + c * 512);
    const float4* p2 = (const float4*)(ws + OFF_PD2 + c * 512);
    float4 a0 = p1[t * 2], a1 = p1[t * 2 + 1], c0 = p2[t * 2], c1 = p2[t * 2 + 1];
    float s1 = a0.x + a0.y + a0.z + a0.w + a1.x + a1.y + a1.z + a1.w;
    float s2 = c0.x + c0.y + c0.z + c0.w + c1.x + c1.y + c1.z + c1.w;
#pragma unroll
    for (int off = 32; off > 0; off >>= 1) {
        s1 += __shfl_xor(s1, off);
        s2 += __shfl_xor(s2, off);
    }
    float mean = s1 / N2f;
    float var = fmaxf(s2 / N2f - mean * mean, 0.f);
    float a = bn2w[c] / sqrtf(var + 1e-3f);
    float bb = bn2b[c] - mean * a;
    const float4* dr = (const float4*)(ws + OFF_DWOUT + (b * 32 + c) * 1024);
#pragma unroll
    for (int q = 0; q < 4; q++) {
        float4 v4 = dr[q * 64 + t];
        ins[8 + q * 64 + t] = 0.25f * (eluf(a * v4.x + bb) + eluf(a * v4.y + bb) +
                                       eluf(a * v4.z + bb) + eluf(a * v4.w + bb));
    }
    __syncthreads();
    float ek[16], bk[16];
#pragma unroll
    for (int k = 0; k < 16; k++) { ek[k] = ec1w[c * 16 + k]; bk[k] = bc1w[c * 16 + k]; }
    for (int w = t; w < 257; w += 64) {
        float s = 0.f;
#pragma unroll
        for (int k = 0; k < 16; k++) s += ins[w + k] * ek[k];
        e1p[8 + w] = s;
    }
    __syncthreads();
    float* e2r = ws + OFF_E2 + (b * 32 + c) * 258;
    for (int w = t; w < 258; w += 64) {
        float s = 0.f;
#pragma unroll
        for (int k = 0; k < 16; k++) s += e1p[w + k] * bk[k];
        e2r[w] = s;
    }
}

// ---------------- K4: b2c2 (1x1 dense) + BN3 stats ----------------
__global__ __launch_bounds__(256) void k_sep2(const float* __restrict__ bc2w,
                                              float* __restrict__ ws) {
    __shared__ float es[32 * 129];
    __shared__ float bs[1056];
    int b = blockIdx.x;
    int wb = blockIdx.y * 129;
    int t = threadIdx.x;
    for (int i = t; i < 1024; i += 256) { int o = i >> 5, cc = i & 31; bs[o * 33 + cc] = bc2w[i]; }
    const float* e2b = ws + OFF_E2 + b * 8256;
    for (int i = t; i < 4128; i += 256) {
        int cc = i / 129, wl = i - cc * 129;
        es[i] = e2b[cc * 258 + wb + wl];
    }
    __syncthreads();
    int o = t >> 3, w0 = t & 7;
    float wr[32];
#pragma unroll
    for (int cc = 0; cc < 32; cc++) wr[cc] = bs[o * 33 + cc];
    float s1 = 0.f, s2 = 0.f;
    float* c3r = ws + OFF_C3 + (b * 32 + o) * 258 + wb;
    for (int wl = w0; wl < 129; wl += 8) {
        float s = 0.f;
#pragma unroll
        for (int cc = 0; cc < 32; cc++) s += es[cc * 129 + wl] * wr[cc];
        c3r[wl] = s;
        s1 += s; s2 += s * s;
    }
    s1 += __shfl_down(s1, 4, 8); s1 += __shfl_down(s1, 2, 8); s1 += __shfl_down(s1, 1, 8);
    s2 += __shfl_down(s2, 4, 8); s2 += __shfl_down(s2, 2, 8); s2 += __shfl_down(s2, 1, 8);
    if (w0 == 0) {
        atomicAdd(&ws[OFF_S1_3 + o], s1);
        atomicAdd(&ws[OFF_S2_3 + o], s2);
    }
}

// ---------------- K5: BN3+ELU+pool4 + normalize + lift + lc1 -> pts ----------------
__global__ __launch_bounds__(256, 1) void k_head(const float* __restrict__ bn3w,
                                                 const float* __restrict__ bn3b,
                                                 const float* __restrict__ lc1w,
                                                 const int* __restrict__ domains,
                                                 float* __restrict__ ws) {
    __shared__ float q[2048];
    __shared__ float lc1s[1089];
    __shared__ float psum[33];
    __shared__ float ssyp[4][64];
    __shared__ float a3s[32], b3s[32];
    int tid = threadIdx.x;
    int b = blockIdx.x;
    if (tid < 32) {
        float mean = ws[OFF_S1_3 + tid] / N3f;
        float var = fmaxf(ws[OFF_S2_3 + tid] / N3f - mean * mean, 0.f);
        float a = bn3w[tid] / sqrtf(var + 1e-3f);
        a3s[tid] = a;
        b3s[tid] = bn3b[tid] - mean * a;
    }
    for (int i = tid; i < 1089; i += 256) lc1s[i] = lc1w[i];
    __syncthreads();
    const float* c3 = ws + OFF_C3 + b * 8256;
    for (int idx = tid; idx < 2048; idx += 256) {
        int c = idx >> 6, wp = idx & 63;
        float a = a3s[c], bb = b3s[c];
        float acc = 0.f;
#pragma unroll
        for (int j = 0; j < 4; j++) {
            float e = a * c3[c * 258 + wp * 4 + j] + bb;
            acc += eluf(e);
        }
        q[idx] = 0.25f * acc;
    }
    __syncthreads();
    int w = tid & 63, sub = tid >> 6;
    float qv[32];
    float ssq = 0.f;
#pragma unroll
    for (int c = 0; c < 32; c++) { qv[c] = q[c * 64 + w]; ssq += qv[c] * qv[c]; }
    float inv = 1.f / fmaxf(sqrtf(ssq), 1e-12f);
    float ss2 = 0.f;
#pragma unroll
    for (int c = 0; c < 32; c++) { qv[c] *= inv; ss2 += qv[c] * qv[c]; }
    float t = sqrtf(1.f + ss2);
    int o0 = 1 + sub * 8;
    float p[8];
    float ssy_part = 0.f;
#pragma unroll
    for (int i = 0; i < 8; i++) {
        int o = o0 + i;
        float s = lc1s[o * 33] * t;
#pragma unroll
        for (int c = 0; c < 32; c++) s += lc1s[o * 33 + 1 + c] * qv[c];
        p[i] = s;
        ssy_part += s * s;
    }
    ssyp[sub][w] = ssy_part;
    float* pr = ws + OFF_PTS + (b * 64 + w) * 33;
#pragma unroll
    for (int i = 0; i < 8; i++) pr[o0 + i] = p[i];
    __syncthreads();
    float yt = 0.f;
    if (sub == 0) {
        float ssy = ssyp[0][w] + ssyp[1][w] + ssyp[2][w] + ssyp[3][w];
        yt = sqrtf(1.f + ssy);
        pr[0] = yt;
    }
#pragma unroll
    for (int i = 0; i < 8; i++) {
        float vv = p[i];
#pragma unroll
        for (int off = 32; off > 0; off >>= 1) vv += __shfl_down(vv, off);
        if (w == 0) psum[o0 + i] = vv;
    }
    {
        float vv = yt;
#pragma unroll
        for (int off = 32; off > 0; off >>= 1) vv += __shfl_down(vv, off);
        if (w == 0 && sub == 0) psum[0] = vv;
    }
    __syncthreads();
    int dom = domains[b];
    if (tid < 33) atomicAdd(&ws[OFF_SEG + dom * 33 + tid], psum[tid]);
    if (tid == 64) atomicAdd(&ws[OFF_CNT + dom], 64.f);
}

// ---------------- K6: mu (inline) + log-map + transport + dist^2 ----------------
__global__ __launch_bounds__(64, 1) void k_tangent(const int* __restrict__ domains,
                                                   float* __restrict__ ws) {
    int b = blockIdx.x;
    int w = threadIdx.x;
    int dom = domains[b];
    float cnt = fmaxf(ws[OFF_CNT + dom], 1.f);
    float m[33];
    float s0 = ws[OFF_SEG + dom * 33] / cnt;
    m[0] = s0;
    float msum = 0.f;
#pragma unroll
    for (int c = 1; c < 33; c++) {
        m[c] = ws[OFF_SEG + dom * 33 + c] / cnt;
        msum += m[c] * m[c];
    }
    float mkm = -s0 * s0 + msum;
    float dn = 1.f / sqrtf(fmaxf(fabsf(mkm), 1e-8f));
#pragma unroll
    for (int c = 0; c < 33; c++) m[c] *= dn;
    const float* pr = ws + OFF_PTS + (b * 64 + w) * 33;
    float p[33];
#pragma unroll
    for (int c = 0; c < 33; c++) p[c] = pr[c];
    float ip = -m[0] * p[0];
#pragma unroll
    for (int c = 1; c < 33; c++) ip += m[c] * p[c];
    float z = fmaxf(-ip, 1.f + 1e-7f);
    float dist = acoshf(z);
    float u[33];
#pragma unroll
    for (int c = 0; c < 33; c++) u[c] = p[c] + ip * m[c];
    float mk = -u[0] * u[0];
#pragma unroll
    for (int c = 1; c < 33; c++) mk += u[c] * u[c];
    float un = sqrtf(fmaxf(mk, 1e-8f));
    float r = dist / un;
    float v0 = r * u[0];
    float coef = -v0 / (1.f + m[0]);
    float* vo = ws + OFF_VO + (b * 64 + w) * 33;
    vo[0] = v0 + coef * (m[0] + 1.f);
#pragma unroll
    for (int c = 1; c < 33; c++) vo[c] = r * u[c] + coef * m[c];
    float dsq = dist * dist;
#pragma unroll
    for (int off = 32; off > 0; off >>= 1) dsq += __shfl_down(dsq, off);
    if (w == 0) atomicAdd(&ws[OFF_DSQ + dom], dsq);
}

// ---------------- K7: scale, transport to beta, expmap, L-ELU, L-pool, MLR ----------
__global__ __launch_bounds__(64, 1) void k_final(const int* __restrict__ domains,
                                                 const float* __restrict__ beta,
                                                 const float* __restrict__ gamma,
                                                 const float* __restrict__ mlr_a,
                                                 const float* __restrict__ mlr_z,
                                                 float* __restrict__ ws,
                                                 float* __restrict__ out) {
    __shared__ float he[64 * 33];
    __shared__ float hp[16 * 33];
    int b = blockIdx.x;
    int w = threadIdx.x;
    int dom = domains[b];
    float cnt = fmaxf(ws[OFF_CNT + dom], 1.f);
    float var = ws[OFF_DSQ + dom] / cnt;
    float sc = gamma[0] / sqrtf(var + 1e-5f);
    float bt[33];
#pragma unroll
    for (int c = 0; c < 33; c++) bt[c] = beta[c];
    const float* vo = ws + OFF_VO + (b * 64 + w) * 33;
    float v[33];
#pragma unroll
    for (int c = 0; c < 33; c++) v[c] = vo[c] * sc;
    float mb = -bt[0] * v[0];
#pragma unroll
    for (int c = 1; c < 33; c++) mb += bt[c] * v[c];
    float coef = mb / (1.f + bt[0]);
    v[0] += coef * (1.f + bt[0]);
#pragma unroll
    for (int c = 1; c < 33; c++) v[c] += coef * bt[c];
    float mk = -v[0] * v[0];
#pragma unroll
    for (int c = 1; c < 33; c++) mk += v[c] * v[c];
    float vn = sqrtf(fmaxf(mk, 1e-8f));
    float ch = coshf(vn), sh = sinhf(vn) / vn;
    float ss = 0.f;
#pragma unroll
    for (int c = 1; c < 33; c++) {
        float y = ch * bt[c] + sh * v[c];
        float s = eluf(y);
        he[w * 33 + c] = s;
        ss += s * s;
    }
    he[w * 33] = sqrtf(1.f + ss);
    __syncthreads();
    if (w < 16) {
        float tmp[33];
        float mk2;
        {
            float a0 = 0.25f * (he[(4 * w) * 33] + he[(4 * w + 1) * 33] +
                                he[(4 * w + 2) * 33] + he[(4 * w + 3) * 33]);
            tmp[0] = a0;
            mk2 = -a0 * a0;
        }
#pragma unroll
        for (int c = 1; c < 33; c++) {
            float a = 0.25f * (he[(4 * w) * 33 + c] + he[(4 * w + 1) * 33 + c] +
                               he[(4 * w + 2) * 33 + c] + he[(4 * w + 3) * 33 + c]);
            tmp[c] = a;
            mk2 += a * a;
        }
        float dd = sqrtf(fmaxf(fabsf(mk2), 1e-8f));
#pragma unroll
        for (int c = 0; c < 33; c++) hp[w * 33 + c] = tmp[c] / dd;
    }
    __syncthreads();
    float ssq = 0.f, sdz = 0.f, zz = 0.f;
    for (int j = w; j < 512; j += 64) {
        float val = hp[(j >> 5) * 33 + 1 + (j & 31)];
        float zv = mlr_z[j];
        ssq += val * val;
        sdz += val * zv;
        zz += zv * zv;
        out[128 + b * 513 + 1 + j] = val;
    }
#pragma unroll
    for (int off = 32; off > 0; off >>= 1) {
        ssq += __shfl_down(ssq, off);
        sdz += __shfl_down(sdz, off);
        zz += __shfl_down(zz, off);
    }
    if (w == 0) {
        float nz = sqrtf(zz);
        float a = mlr_a[0];
        float cha = coshf(a);
        float wt = sinhf(a) * nz;
        float cn = cha * nz;
        float bet = sqrtf(fmaxf(cn * cn - wt * wt, 1e-8f));
        float ft = sqrtf(1.f + ssq);
        float alpha = -wt * ft + cha * sdz;
        out[128 + b * 513] = ft;
        out[b] = bet * asinhf(alpha / bet);
    }
}

extern "C" void kernel_launch(void* const* d_in, const int* in_sizes, int n_in,
                              void* d_out, int out_size, void* d_ws, size_t ws_size,
                              hipStream_t stream) {
    const float* x       = (const float*)d_in[0];
    const int*   domains = (const int*)d_in[1];
    const float* conv1_w = (const float*)d_in[2];
    const float* bn1_w   = (const float*)d_in[3];
    const float* bn1_b   = (const float*)d_in[4];
    const float* dw_w    = (const float*)d_in[5];
    const float* bn2_w   = (const float*)d_in[6];
    const float* bn2_b   = (const float*)d_in[7];
    const float* ec1_w   = (const float*)d_in[8];
    const float* b2c1_w  = (const float*)d_in[9];
    const float* b2c2_w  = (const float*)d_in[10];
    const float* bn3_w   = (const float*)d_in[11];
    const float* bn3_b   = (const float*)d_in[12];
    const float* lc1_w   = (const float*)d_in[13];
    const float* bn_beta = (const float*)d_in[14];
    const float* bn_gamma= (const float*)d_in[15];
    const float* mlr_a   = (const float*)d_in[16];
    const float* mlr_z   = (const float*)d_in[17];
    float* out = (float*)d_out;
    float* ws  = (float*)d_ws;

    hipMemsetAsync(ws, 0, ZERO_N * sizeof(float), stream);
    k_edge<<<64, 256, 0, stream>>>(x, ws);
    k_corr<<<1024, 256, 0, stream>>>(x, ws);
    k_fold<<<1, 512, 0, stream>>>(conv1_w, bn1_w, bn1_b, ws);
    k_dw<<<dim3(128, 4), 256, 0, stream>>>(x, conv1_w, dw_w, ws);
    k_pe<<<dim3(128, 32), 64, 0, stream>>>(ec1_w, b2c1_w, bn2_w, bn2_b, ws);
    k_sep2<<<dim3(128, 2), 256, 0, stream>>>(b2c2_w, ws);
    k_head<<<Bn, 256, 0, stream>>>(bn3_w, bn3_b, lc1_w, domains, ws);
    k_tangent<<<Bn, 64, 0, stream>>>(domains, ws);
    k_final<<<Bn, 64, 0, stream>>>(domains, bn_beta, bn_gamma, mlr_a, mlr_z, ws, out);
}